// Round 1
// baseline (1019.843 us; speedup 1.0000x reference)
//
#include <hip/hip_runtime.h>
#include <math.h>

#define H 8

// ---- Layer 1 edge aggregation: agg1[dst] += x[src], scalar messages ----
__global__ void edge_agg1(const int* __restrict__ ei, const float* __restrict__ x,
                          float* __restrict__ agg1, int E) {
    int e = blockIdx.x * blockDim.x + threadIdx.x;
    if (e >= E) return;
    int src = ei[e];
    int dst = ei[E + e];
    atomicAdd(&agg1[dst], x[src]);
}

// ---- Layer 1 node MLP: h1 = elu(relu((x+agg1) @ W1a + b1a) @ W1b + b1b) ----
__global__ void node1(const float* __restrict__ x, const float* __restrict__ agg1,
                      const float* __restrict__ W1a, const float* __restrict__ b1a,
                      const float* __restrict__ W1b, const float* __restrict__ b1b,
                      float* __restrict__ h1, int N) {
    __shared__ float sW1a[H], sb1a[H], sW1b[H * H], sb1b[H];
    int t = threadIdx.x;
    if (t < H) { sW1a[t] = W1a[t]; sb1a[t] = b1a[t]; sb1b[t] = b1b[t]; }
    if (t < H * H) sW1b[t] = W1b[t];
    __syncthreads();
    int n = blockIdx.x * blockDim.x + t;
    if (n >= N) return;
    float z = x[n] + agg1[n];
    float tv[H];
#pragma unroll
    for (int k = 0; k < H; k++) tv[k] = fmaxf(z * sW1a[k] + sb1a[k], 0.f);
    float h[H];
#pragma unroll
    for (int j = 0; j < H; j++) {
        float acc = sb1b[j];
#pragma unroll
        for (int k = 0; k < H; k++) acc += tv[k] * sW1b[k * H + j];
        h[j] = acc > 0.f ? acc : (expf(acc) - 1.f);  // elu
    }
    float4* out = (float4*)(h1 + (size_t)n * H);
    out[0] = make_float4(h[0], h[1], h[2], h[3]);
    out[1] = make_float4(h[4], h[5], h[6], h[7]);
}

// ---- Layer 2 edge aggregation: agg2[dst][k] += h1[src][k]; thread per (edge,feature) ----
__global__ void edge_agg2(const int* __restrict__ ei, const float* __restrict__ h1,
                          float* __restrict__ agg2, int E) {
    long long i = (long long)blockIdx.x * blockDim.x + threadIdx.x;
    if (i >= (long long)E * H) return;
    int e = (int)(i >> 3);
    int k = (int)(i & 7);
    int src = ei[e];
    int dst = ei[E + e];
    atomicAdd(&agg2[(size_t)dst * H + k], h1[(size_t)src * H + k]);
}

// ---- Layer 2 node MLP + pooled segment-sum ----
__global__ void node2_pool(const float* __restrict__ h1, const float* __restrict__ agg2,
                           const float* __restrict__ W2a, const float* __restrict__ b2a,
                           const float* __restrict__ W2b, const float* __restrict__ b2b,
                           const int* __restrict__ batch,
                           float* __restrict__ sums, float* __restrict__ counts, int N) {
    __shared__ float sW2a[H * H], sb2a[H], sW2b[H * H], sb2b[H];
    int t = threadIdx.x;
    if (t < H) { sb2a[t] = b2a[t]; sb2b[t] = b2b[t]; }
    if (t < H * H) { sW2a[t] = W2a[t]; sW2b[t] = W2b[t]; }
    __syncthreads();
    int n = blockIdx.x * blockDim.x + t;
    if (n >= N) return;
    const float4* hv = (const float4*)(h1 + (size_t)n * H);
    const float4* gv = (const float4*)(agg2 + (size_t)n * H);
    float4 a0 = hv[0], a1 = hv[1], g0 = gv[0], g1 = gv[1];
    float z[H] = {a0.x + g0.x, a0.y + g0.y, a0.z + g0.z, a0.w + g0.w,
                  a1.x + g1.x, a1.y + g1.y, a1.z + g1.z, a1.w + g1.w};
    float tv[H];
#pragma unroll
    for (int k = 0; k < H; k++) {
        float acc = sb2a[k];
#pragma unroll
        for (int j = 0; j < H; j++) acc += z[j] * sW2a[j * H + k];
        tv[k] = fmaxf(acc, 0.f);
    }
    int g = batch[n];
#pragma unroll
    for (int j = 0; j < H; j++) {
        float acc = sb2b[j];
#pragma unroll
        for (int k = 0; k < H; k++) acc += tv[k] * sW2b[k * H + j];
        atomicAdd(&sums[(size_t)g * H + j], acc);
    }
    atomicAdd(&counts[g], 1.f);
}

// ---- Final: out[g] = sigmoid((sums[g]/max(count,1)) @ Wfc + bfc) ----
__global__ void final_k(const float* __restrict__ sums, const float* __restrict__ counts,
                        const float* __restrict__ Wfc, const float* __restrict__ bfc,
                        float* __restrict__ out, int G) {
    int g = blockIdx.x * blockDim.x + threadIdx.x;
    if (g >= G) return;
    float c = fmaxf(counts[g], 1.f);
    float acc = bfc[0];
#pragma unroll
    for (int j = 0; j < H; j++) acc += (sums[(size_t)g * H + j] / c) * Wfc[j];
    out[g] = 1.f / (1.f + expf(-acc));
}

extern "C" void kernel_launch(void* const* d_in, const int* in_sizes, int n_in,
                              void* d_out, int out_size, void* d_ws, size_t ws_size,
                              hipStream_t stream) {
    const float* x    = (const float*)d_in[0];
    const int*   ei   = (const int*)d_in[1];
    const int*   batch= (const int*)d_in[2];
    const float* W1a  = (const float*)d_in[3];
    const float* b1a  = (const float*)d_in[4];
    const float* W1b  = (const float*)d_in[5];
    const float* b1b  = (const float*)d_in[6];
    const float* W2a  = (const float*)d_in[7];
    const float* b2a  = (const float*)d_in[8];
    const float* W2b  = (const float*)d_in[9];
    const float* b2b  = (const float*)d_in[10];
    const float* Wfc  = (const float*)d_in[11];
    const float* bfc  = (const float*)d_in[12];

    const int N = in_sizes[0];
    const int E = in_sizes[1] / 2;
    const int G = out_size;

    float* ws     = (float*)d_ws;
    float* agg1   = ws;                       // N
    float* agg2   = agg1 + (size_t)N;         // 8N
    float* sums   = agg2 + (size_t)8 * N;     // 8G
    float* counts = sums + (size_t)8 * G;     // G
    float* h1     = counts + (size_t)G;       // 8N  (not zeroed; fully written)

    size_t zero_elems = (size_t)9 * N + (size_t)9 * G;
    hipMemsetAsync(ws, 0, zero_elems * sizeof(float), stream);

    const int B = 256;
    edge_agg1<<<(E + B - 1) / B, B, 0, stream>>>(ei, x, agg1, E);
    node1<<<(N + B - 1) / B, B, 0, stream>>>(x, agg1, W1a, b1a, W1b, b1b, h1, N);
    long long tot = (long long)E * H;
    edge_agg2<<<(int)((tot + B - 1) / B), B, 0, stream>>>(ei, h1, agg2, E);
    node2_pool<<<(N + B - 1) / B, B, 0, stream>>>(h1, agg2, W2a, b2a, W2b, b2b, batch,
                                                  sums, counts, N);
    final_k<<<(G + B - 1) / B, B, 0, stream>>>(sums, counts, Wfc, bfc, (float*)d_out, G);
}

// Round 2
// 630.619 us; speedup vs baseline: 1.6172x; 1.6172x over previous
//
#include <hip/hip_runtime.h>
#include <math.h>

#define H 8
#define NBLKA 256          // blocks for hist/scatter passes
#define BSH 8              // bucket shift: 256 nodes per bucket

// ============================ FAST PATH ============================

// Phase A: per-block LDS histogram of dst buckets
__global__ void histK(const int* __restrict__ ei, int E, int NB, int chunk,
                      int* __restrict__ hist, int* __restrict__ bucketTotal) {
    __shared__ int h[1024];
    int t = threadIdx.x, blk = blockIdx.x;
    for (int j = t; j < NB; j += 256) h[j] = 0;
    __syncthreads();
    int s = blk * chunk, e = min(E, s + chunk);
    for (int i = s + t; i < e; i += 256)
        atomicAdd(&h[ei[E + i] >> BSH], 1);
    __syncthreads();
    for (int j = t; j < NB; j += 256) {
        int v = h[j];
        hist[blk * NB + j] = v;
        if (v) atomicAdd(&bucketTotal[j], v);
    }
}

// Phase B1: exclusive scan over bucket totals (1 block, 1024 threads)
__global__ void scanBuckets(const int* __restrict__ bucketTotal, int NB,
                            int* __restrict__ bucketStart) {
    __shared__ int s[1024];
    int t = threadIdx.x;
    int my = (t < NB) ? bucketTotal[t] : 0;
    s[t] = my;
    __syncthreads();
    for (int off = 1; off < 1024; off <<= 1) {
        int v = (t >= off) ? s[t - off] : 0;
        __syncthreads();
        s[t] += v;
        __syncthreads();
    }
    if (t < NB) bucketStart[t] = s[t] - my;      // exclusive
    if (t == NB - 1) bucketStart[NB] = s[t];     // total = E
}

// Phase B2: per-(block,bucket) start offsets
__global__ void blockOffsets(const int* __restrict__ hist, const int* __restrict__ bucketStart,
                             int NB, int* __restrict__ blockStart) {
    __shared__ int s[256];
    int t = threadIdx.x, b = blockIdx.x;
    int my = hist[t * NB + b];
    s[t] = my;
    __syncthreads();
    for (int off = 1; off < 256; off <<= 1) {
        int v = (t >= off) ? s[t - off] : 0;
        __syncthreads();
        s[t] += v;
        __syncthreads();
    }
    blockStart[t * NB + b] = bucketStart[b] + (s[t] - my);
}

// Phase C: scatter edges into bucket-contiguous (src,dst) pairs
__global__ void scatterK(const int* __restrict__ ei, int E, int NB, int chunk,
                         const int* __restrict__ blockStart, int2* __restrict__ sortedE) {
    __shared__ int cur[1024];
    int t = threadIdx.x, blk = blockIdx.x;
    for (int j = t; j < NB; j += 256) cur[j] = blockStart[blk * NB + j];
    __syncthreads();
    int s = blk * chunk, e = min(E, s + chunk);
    for (int i = s + t; i < e; i += 256) {
        int src = ei[i], dst = ei[E + i];
        int slot = atomicAdd(&cur[dst >> BSH], 1);
        sortedE[slot] = make_int2(src, dst);
    }
}

// Phase D1: layer-1 aggregation (LDS, bucket-exclusive) + MLP1 + ELU -> h1
__global__ void layer1K(const int2* __restrict__ sortedE, const int* __restrict__ bucketStart,
                        const float* __restrict__ x, int N,
                        const float* __restrict__ W1a, const float* __restrict__ b1a,
                        const float* __restrict__ W1b, const float* __restrict__ b1b,
                        float* __restrict__ h1) {
    __shared__ float acc[256];
    __shared__ float sW1a[H], sb1a[H], sW1b[H * H], sb1b[H];
    int t = threadIdx.x, b = blockIdx.x;
    acc[t] = 0.f;
    if (t < H) { sW1a[t] = W1a[t]; sb1a[t] = b1a[t]; sb1b[t] = b1b[t]; }
    if (t < H * H) sW1b[t] = W1b[t];
    __syncthreads();
    int s = bucketStart[b], e = bucketStart[b + 1];
    for (int i = s + t; i < e; i += 256) {
        int2 sd = sortedE[i];
        atomicAdd(&acc[sd.y & 255], x[sd.x]);
    }
    __syncthreads();
    int n = (b << BSH) + t;
    if (n < N) {
        float z = x[n] + acc[t];
        float tv[H];
#pragma unroll
        for (int k = 0; k < H; k++) tv[k] = fmaxf(fmaf(z, sW1a[k], sb1a[k]), 0.f);
        float hv[H];
#pragma unroll
        for (int j = 0; j < H; j++) {
            float a = sb1b[j];
#pragma unroll
            for (int k = 0; k < H; k++) a += tv[k] * sW1b[k * H + j];
            hv[j] = a > 0.f ? a : (expf(a) - 1.f);   // elu
        }
        float4* out = (float4*)(h1 + (size_t)n * H);
        out[0] = make_float4(hv[0], hv[1], hv[2], hv[3]);
        out[1] = make_float4(hv[4], hv[5], hv[6], hv[7]);
    }
}

// Phase D2: layer-2 aggregation (LDS) + MLP2 + block-segmented pooling
__global__ void layer2K(const int2* __restrict__ sortedE, const int* __restrict__ bucketStart,
                        const float* __restrict__ h1, int N,
                        const float* __restrict__ W2a, const float* __restrict__ b2a,
                        const float* __restrict__ W2b, const float* __restrict__ b2b,
                        const int* __restrict__ batch, float* __restrict__ sumsCnt) {
    __shared__ float scratch[2304];                 // 256*8 acc, then reused as 256*9 pool
    __shared__ float sW2a[H * H], sb2a[H], sW2b[H * H], sb2b[H];
    int t = threadIdx.x, b = blockIdx.x;
    for (int j = t; j < 2048; j += 256) scratch[j] = 0.f;
    if (t < H * H) { sW2a[t] = W2a[t]; sW2b[t] = W2b[t]; }
    if (t < H) { sb2a[t] = b2a[t]; sb2b[t] = b2b[t]; }
    __syncthreads();
    int s = bucketStart[b], e = bucketStart[b + 1];
    const float4* h1v = (const float4*)h1;
    for (int i = s + t; i < e; i += 256) {
        int2 sd = sortedE[i];
        float4 a0 = h1v[(size_t)sd.x * 2];
        float4 a1 = h1v[(size_t)sd.x * 2 + 1];
        float* p = &scratch[(sd.y & 255) * H];
        atomicAdd(p + 0, a0.x); atomicAdd(p + 1, a0.y);
        atomicAdd(p + 2, a0.z); atomicAdd(p + 3, a0.w);
        atomicAdd(p + 4, a1.x); atomicAdd(p + 5, a1.y);
        atomicAdd(p + 6, a1.z); atomicAdd(p + 7, a1.w);
    }
    __syncthreads();
    int n = (b << BSH) + t;
    bool valid = n < N;
    float h2[H];
    int g = 0;
    if (valid) {
        float4 m0 = h1v[(size_t)n * 2], m1 = h1v[(size_t)n * 2 + 1];
        float z[H] = {m0.x + scratch[t * H + 0], m0.y + scratch[t * H + 1],
                      m0.z + scratch[t * H + 2], m0.w + scratch[t * H + 3],
                      m1.x + scratch[t * H + 4], m1.y + scratch[t * H + 5],
                      m1.z + scratch[t * H + 6], m1.w + scratch[t * H + 7]};
        float tv[H];
#pragma unroll
        for (int k = 0; k < H; k++) {
            float a = sb2a[k];
#pragma unroll
            for (int j = 0; j < H; j++) a += z[j] * sW2a[j * H + k];
            tv[k] = fmaxf(a, 0.f);
        }
#pragma unroll
        for (int j = 0; j < H; j++) {
            float a = sb2b[j];
#pragma unroll
            for (int k = 0; k < H; k++) a += tv[k] * sW2b[k * H + j];
            h2[j] = a;
        }
        g = batch[n];
    }
    int gfirst = batch[b << BSH];
    int glast  = batch[min((b << BSH) + 255, N - 1)];
    int span9 = (glast - gfirst + 1) * 9;
    __syncthreads();                                 // done reading acc region
    for (int j = t; j < span9; j += 256) scratch[j] = 0.f;
    __syncthreads();
    if (valid) {
        float* p = &scratch[(g - gfirst) * 9];
#pragma unroll
        for (int j = 0; j < H; j++) atomicAdd(p + j, h2[j]);
        atomicAdd(p + 8, 1.f);
    }
    __syncthreads();
    for (int j = t; j < span9; j += 256)
        atomicAdd(&sumsCnt[(size_t)gfirst * 9 + j], scratch[j]);
}

__global__ void finalK(const float* __restrict__ sumsCnt, const float* __restrict__ Wfc,
                       const float* __restrict__ bfc, float* __restrict__ out, int G) {
    int g = blockIdx.x * blockDim.x + threadIdx.x;
    if (g >= G) return;
    const float* s = &sumsCnt[(size_t)g * 9];
    float c = fmaxf(s[8], 1.f);
    float dot = 0.f;
#pragma unroll
    for (int j = 0; j < H; j++) dot += s[j] * Wfc[j];
    float a = dot / c + bfc[0];
    out[g] = 1.f / (1.f + expf(-a));
}

// ============================ FALLBACK (R1 atomic path) ============================

__global__ void edge_agg1(const int* __restrict__ ei, const float* __restrict__ x,
                          float* __restrict__ agg1, int E) {
    int e = blockIdx.x * blockDim.x + threadIdx.x;
    if (e >= E) return;
    atomicAdd(&agg1[ei[E + e]], x[ei[e]]);
}
__global__ void node1(const float* __restrict__ x, const float* __restrict__ agg1,
                      const float* __restrict__ W1a, const float* __restrict__ b1a,
                      const float* __restrict__ W1b, const float* __restrict__ b1b,
                      float* __restrict__ h1, int N) {
    __shared__ float sW1a[H], sb1a[H], sW1b[H * H], sb1b[H];
    int t = threadIdx.x;
    if (t < H) { sW1a[t] = W1a[t]; sb1a[t] = b1a[t]; sb1b[t] = b1b[t]; }
    if (t < H * H) sW1b[t] = W1b[t];
    __syncthreads();
    int n = blockIdx.x * blockDim.x + t;
    if (n >= N) return;
    float z = x[n] + agg1[n];
    float tv[H];
#pragma unroll
    for (int k = 0; k < H; k++) tv[k] = fmaxf(z * sW1a[k] + sb1a[k], 0.f);
    float h[H];
#pragma unroll
    for (int j = 0; j < H; j++) {
        float acc = sb1b[j];
#pragma unroll
        for (int k = 0; k < H; k++) acc += tv[k] * sW1b[k * H + j];
        h[j] = acc > 0.f ? acc : (expf(acc) - 1.f);
    }
    float4* out = (float4*)(h1 + (size_t)n * H);
    out[0] = make_float4(h[0], h[1], h[2], h[3]);
    out[1] = make_float4(h[4], h[5], h[6], h[7]);
}
__global__ void edge_agg2(const int* __restrict__ ei, const float* __restrict__ h1,
                          float* __restrict__ agg2, int E) {
    long long i = (long long)blockIdx.x * blockDim.x + threadIdx.x;
    if (i >= (long long)E * H) return;
    int e = (int)(i >> 3), k = (int)(i & 7);
    atomicAdd(&agg2[(size_t)ei[E + e] * H + k], h1[(size_t)ei[e] * H + k]);
}
__global__ void node2_pool(const float* __restrict__ h1, const float* __restrict__ agg2,
                           const float* __restrict__ W2a, const float* __restrict__ b2a,
                           const float* __restrict__ W2b, const float* __restrict__ b2b,
                           const int* __restrict__ batch,
                           float* __restrict__ sums, float* __restrict__ counts, int N) {
    __shared__ float sW2a[H * H], sb2a[H], sW2b[H * H], sb2b[H];
    int t = threadIdx.x;
    if (t < H) { sb2a[t] = b2a[t]; sb2b[t] = b2b[t]; }
    if (t < H * H) { sW2a[t] = W2a[t]; sW2b[t] = W2b[t]; }
    __syncthreads();
    int n = blockIdx.x * blockDim.x + t;
    if (n >= N) return;
    const float4* hv = (const float4*)(h1 + (size_t)n * H);
    const float4* gv = (const float4*)(agg2 + (size_t)n * H);
    float4 a0 = hv[0], a1 = hv[1], g0 = gv[0], g1 = gv[1];
    float z[H] = {a0.x + g0.x, a0.y + g0.y, a0.z + g0.z, a0.w + g0.w,
                  a1.x + g1.x, a1.y + g1.y, a1.z + g1.z, a1.w + g1.w};
    float tv[H];
#pragma unroll
    for (int k = 0; k < H; k++) {
        float acc = sb2a[k];
#pragma unroll
        for (int j = 0; j < H; j++) acc += z[j] * sW2a[j * H + k];
        tv[k] = fmaxf(acc, 0.f);
    }
    int g = batch[n];
#pragma unroll
    for (int j = 0; j < H; j++) {
        float acc = sb2b[j];
#pragma unroll
        for (int k = 0; k < H; k++) acc += tv[k] * sW2b[k * H + j];
        atomicAdd(&sums[(size_t)g * H + j], acc);
    }
    atomicAdd(&counts[g], 1.f);
}
__global__ void final_old(const float* __restrict__ sums, const float* __restrict__ counts,
                          const float* __restrict__ Wfc, const float* __restrict__ bfc,
                          float* __restrict__ out, int G) {
    int g = blockIdx.x * blockDim.x + threadIdx.x;
    if (g >= G) return;
    float c = fmaxf(counts[g], 1.f);
    float acc = bfc[0];
#pragma unroll
    for (int j = 0; j < H; j++) acc += (sums[(size_t)g * H + j] / c) * Wfc[j];
    out[g] = 1.f / (1.f + expf(-acc));
}

// ============================ LAUNCH ============================

extern "C" void kernel_launch(void* const* d_in, const int* in_sizes, int n_in,
                              void* d_out, int out_size, void* d_ws, size_t ws_size,
                              hipStream_t stream) {
    const float* x    = (const float*)d_in[0];
    const int*   ei   = (const int*)d_in[1];
    const int*   batch= (const int*)d_in[2];
    const float* W1a  = (const float*)d_in[3];
    const float* b1a  = (const float*)d_in[4];
    const float* W1b  = (const float*)d_in[5];
    const float* b1b  = (const float*)d_in[6];
    const float* W2a  = (const float*)d_in[7];
    const float* b2a  = (const float*)d_in[8];
    const float* W2b  = (const float*)d_in[9];
    const float* b2b  = (const float*)d_in[10];
    const float* Wfc  = (const float*)d_in[11];
    const float* bfc  = (const float*)d_in[12];

    const int N = in_sizes[0];
    const int E = in_sizes[1] / 2;
    const int G = out_size;
    const int NB = (N + 255) >> BSH;
    const int chunk = (E + NBLKA - 1) / NBLKA;
    const int B = 256;

    // fast-path workspace layout (units: 4-byte elements)
    size_t o_bt   = 0;                          // bucketTotal   [1024]
    size_t o_hist = 1024;                       // hist          [NBLKA*NB]
    size_t o_sc   = o_hist + (size_t)NBLKA*NB;  // sumsCnt       [9*G]
    size_t zelems = o_sc + (size_t)9*G;         // ---- memset up to here ----
    size_t o_bs   = (zelems + 3) & ~(size_t)3;  // bucketStart   [NB+1] (pad)
    size_t o_bo   = (o_bs + NB + 1 + 3) & ~(size_t)3; // blockStart [NBLKA*NB]
    size_t o_se   = (o_bo + (size_t)NBLKA*NB + 3) & ~(size_t)3;  // sortedE [2*E]
    if (o_se & 1) o_se++;                       // 8B align for int2
    size_t o_h1   = (o_se + 2*(size_t)E + 3) & ~(size_t)3;       // h1 [8*N]
    size_t total  = o_h1 + 8*(size_t)N;

    if (NB <= 1024 && ws_size >= total * 4) {
        int*   wsi = (int*)d_ws;
        float* wsf = (float*)d_ws;
        int*   bucketTotal = wsi + o_bt;
        int*   hist        = wsi + o_hist;
        float* sumsCnt     = wsf + o_sc;
        int*   bucketStart = wsi + o_bs;
        int*   blockStart  = wsi + o_bo;
        int2*  sortedE     = (int2*)(wsi + o_se);
        float* h1          = wsf + o_h1;

        hipMemsetAsync(d_ws, 0, zelems * 4, stream);
        histK<<<NBLKA, B, 0, stream>>>(ei, E, NB, chunk, hist, bucketTotal);
        scanBuckets<<<1, 1024, 0, stream>>>(bucketTotal, NB, bucketStart);
        blockOffsets<<<NB, NBLKA, 0, stream>>>(hist, bucketStart, NB, blockStart);
        scatterK<<<NBLKA, B, 0, stream>>>(ei, E, NB, chunk, blockStart, sortedE);
        layer1K<<<NB, B, 0, stream>>>(sortedE, bucketStart, x, N, W1a, b1a, W1b, b1b, h1);
        layer2K<<<NB, B, 0, stream>>>(sortedE, bucketStart, h1, N, W2a, b2a, W2b, b2b,
                                      batch, sumsCnt);
        finalK<<<(G + B - 1) / B, B, 0, stream>>>(sumsCnt, Wfc, bfc, (float*)d_out, G);
    } else {
        // fallback: R1 atomic path
        float* ws     = (float*)d_ws;
        float* agg1   = ws;
        float* agg2   = agg1 + (size_t)N;
        float* sums   = agg2 + (size_t)8 * N;
        float* counts = sums + (size_t)8 * G;
        float* h1     = counts + (size_t)G;
        hipMemsetAsync(ws, 0, ((size_t)9 * N + (size_t)9 * G) * sizeof(float), stream);
        edge_agg1<<<(E + B - 1) / B, B, 0, stream>>>(ei, x, agg1, E);
        node1<<<(N + B - 1) / B, B, 0, stream>>>(x, agg1, W1a, b1a, W1b, b1b, h1, N);
        long long tot = (long long)E * H;
        edge_agg2<<<(int)((tot + B - 1) / B), B, 0, stream>>>(ei, h1, agg2, E);
        node2_pool<<<(N + B - 1) / B, B, 0, stream>>>(h1, agg2, W2a, b2a, W2b, b2b, batch,
                                                      sums, counts, N);
        final_old<<<(G + B - 1) / B, B, 0, stream>>>(sums, counts, Wfc, bfc, (float*)d_out, G);
    }
}